// Round 1
// baseline (188.850 us; speedup 1.0000x reference)
//
#include <hip/hip_runtime.h>
#include <math.h>

#define TPB 256
#define ROWS 8
#define ROWSTRIDE 1280          // 32 chunks * 40 floats (pad 32->40 per chunk)
#define LDS_FLOATS (ROWS * ROWSTRIDE)

// padded column index: chunk (c>>5) stride 40 floats instead of 32
__device__ __forceinline__ unsigned cidx(unsigned c) {
    return c + ((c >> 5) << 3);
}

__device__ __forceinline__ float sigm(float v) {
    return 1.0f / (1.0f + expf(-v));
}

__device__ __forceinline__ void probs(const float* __restrict__ lg, int i,
                                      float& p, float& p1, float& p2) {
    p  = sigm(lg[3 * i + 0]);
    p1 = sigm(lg[3 * i + 1]);
    p2 = sigm(lg[3 * i + 2]);
}

// One stage (block size N) done in LDS. Pairs (j, mirror(j)) share 4 inputs.
template<int N>
__device__ __forceinline__ void lds_stage(float* lds, const unsigned* rowbase,
                                          const unsigned* prA,
                                          float p, float p1, float p2) {
    constexpr unsigned H = N / 2;
    constexpr unsigned Q = N / 4;
    float res[32];
    #pragma unroll
    for (int k = 0; k < 16; ++k) {
        unsigned pr = prA[k];
        unsigned rb = rowbase[k];
        unsigned b    = pr / H;          // block index within row
        unsigned bc   = b * N;           // block base col
        unsigned w    = pr - b * H;      // pair index within block [0, N/2)
        unsigned half = w / Q;           // 0 = lo half, 1 = hi half
        unsigned u    = w - half * Q;    // pair index within half [0, N/4)
        unsigned hb   = bc + half * H;
        unsigned j    = hb + u;
        unsigned jm   = hb + (H - 1 - u);
        unsigned ej   = bc + 2 * u + half;
        unsigned ejm  = bc + 2 * (H - 1 - u) + half;
        float q = half ? p2 : p1;
        float yj   = lds[rb + cidx(j)];
        float yjm  = lds[rb + cidx(jm)];
        float yej  = lds[rb + cidx(ej)];
        float yejm = lds[rb + cidx(ejm)];
        float a0 = fmaf(p, yej  - yj,  yj);   // even_odd at j
        float a1 = fmaf(p, yejm - yjm, yjm);  // even_odd at mirror
        res[2 * k]     = fmaf(q, a1 - a0, a0);  // reverse mix
        res[2 * k + 1] = fmaf(q, a0 - a1, a1);
    }
    __syncthreads();
    #pragma unroll
    for (int k = 0; k < 16; ++k) {
        unsigned pr = prA[k];
        unsigned rb = rowbase[k];
        unsigned b    = pr / H;
        unsigned bc   = b * N;
        unsigned w    = pr - b * H;
        unsigned half = w / Q;
        unsigned u    = w - half * Q;
        unsigned hb   = bc + half * H;
        unsigned j    = hb + u;
        unsigned jm   = hb + (H - 1 - u);
        lds[rb + cidx(j)]  = res[2 * k];
        lds[rb + cidx(jm)] = res[2 * k + 1];
    }
    __syncthreads();
}

// One stage (block size N <= 32) fully inside one thread's 32-element chunk.
template<int N>
__device__ __forceinline__ void reg_stage(float* arr, float p, float p1, float p2) {
    constexpr int H = N / 2;
    float tmp[32];
    #pragma unroll
    for (int bb = 0; bb < 32; bb += N) {
        #pragma unroll
        for (int u = 0; u < N / 4; ++u) {
            {   // lo half pair
                int j = bb + u, jm = bb + H - 1 - u;
                int ej = bb + 2 * u, ejm = bb + 2 * H - 2 - 2 * u;
                float a0 = fmaf(p, arr[ej]  - arr[j],  arr[j]);
                float a1 = fmaf(p, arr[ejm] - arr[jm], arr[jm]);
                tmp[j]  = fmaf(p1, a1 - a0, a0);
                tmp[jm] = fmaf(p1, a0 - a1, a1);
            }
            {   // hi half pair
                int j = bb + H + u, jm = bb + 2 * H - 1 - u;
                int ej = bb + 2 * u + 1, ejm = bb + 2 * H - 1 - 2 * u;
                float a0 = fmaf(p, arr[ej]  - arr[j],  arr[j]);
                float a1 = fmaf(p, arr[ejm] - arr[jm], arr[jm]);
                tmp[j]  = fmaf(p2, a1 - a0, a0);
                tmp[jm] = fmaf(p2, a0 - a1, a1);
            }
        }
    }
    #pragma unroll
    for (int v = 0; v < 32; ++v) arr[v] = tmp[v];
}

__global__ __launch_bounds__(TPB) void bpp_kernel(const float* __restrict__ x,
                                                  const float* __restrict__ logits,
                                                  float* __restrict__ out) {
    __shared__ float lds[LDS_FLOATS];
    const unsigned t = threadIdx.x;
    const size_t gbase = (size_t)blockIdx.x * (ROWS * 1024);

    // coalesced global -> LDS (padded layout)
    const float4* __restrict__ gin = (const float4*)(x + gbase);
    #pragma unroll
    for (int k = 0; k < 8; ++k) {
        unsigned f4 = k * TPB + t;            // float4 index in group [0,2048)
        float4 v = gin[f4];
        unsigned r  = f4 >> 8;                // row in group
        unsigned c4 = (f4 << 2) & 1023u;      // col (multiple of 4)
        *(float4*)&lds[r * ROWSTRIDE + cidx(c4)] = v;
    }
    __syncthreads();

    // per-thread pair-slot decode tables (stage-independent)
    unsigned rowbase[16], prA[16];
    #pragma unroll
    for (int k = 0; k < 16; ++k) {
        unsigned g = t + k * TPB;             // pair id in [0, 4096)
        rowbase[k] = (g >> 9) * ROWSTRIDE;    // 512 pairs per row
        prA[k] = g & 511u;
    }

    {   // stages n = 1024..64 in LDS (logits rows 8..4)
        float p, p1, p2;
        probs(logits, 8, p, p1, p2); lds_stage<1024>(lds, rowbase, prA, p, p1, p2);
        probs(logits, 7, p, p1, p2); lds_stage<512>(lds, rowbase, prA, p, p1, p2);
        probs(logits, 6, p, p1, p2); lds_stage<256>(lds, rowbase, prA, p, p1, p2);
        probs(logits, 5, p, p1, p2); lds_stage<128>(lds, rowbase, prA, p, p1, p2);
        probs(logits, 4, p, p1, p2); lds_stage<64>(lds, rowbase, prA, p, p1, p2);
    }

    // stages n = 32..4 in registers: thread owns one contiguous 32-col chunk
    {
        float arr[32];
        unsigned r = t >> 5, w = t & 31u;
        unsigned cb = r * ROWSTRIDE + w * 40u;
        #pragma unroll
        for (int u = 0; u < 8; ++u)
            *(float4*)&arr[4 * u] = *(const float4*)&lds[cb + 4 * u];
        float p, p1, p2;
        probs(logits, 3, p, p1, p2); reg_stage<32>(arr, p, p1, p2);
        probs(logits, 2, p, p1, p2); reg_stage<16>(arr, p, p1, p2);
        probs(logits, 1, p, p1, p2); reg_stage<8>(arr, p, p1, p2);
        probs(logits, 0, p, p1, p2); reg_stage<4>(arr, p, p1, p2);
        #pragma unroll
        for (int u = 0; u < 8; ++u)
            *(float4*)&lds[cb + 4 * u] = *(const float4*)&arr[4 * u];
    }
    __syncthreads();

    // coalesced LDS -> global
    float4* __restrict__ gout = (float4*)(out + gbase);
    #pragma unroll
    for (int k = 0; k < 8; ++k) {
        unsigned f4 = k * TPB + t;
        unsigned r  = f4 >> 8;
        unsigned c4 = (f4 << 2) & 1023u;
        gout[f4] = *(const float4*)&lds[r * ROWSTRIDE + cidx(c4)];
    }
}

extern "C" void kernel_launch(void* const* d_in, const int* in_sizes, int n_in,
                              void* d_out, int out_size, void* d_ws, size_t ws_size,
                              hipStream_t stream) {
    const float* x      = (const float*)d_in[0];
    const float* logits = (const float*)d_in[1];
    float* out = (float*)d_out;
    int rows = in_sizes[0] / 1024;
    int grid = rows / ROWS;
    bpp_kernel<<<dim3(grid), dim3(TPB), 0, stream>>>(x, logits, out);
}

// Round 3
// 137.712 us; speedup vs baseline: 1.3713x; 1.3713x over previous
//
#include <hip/hip_runtime.h>
#include <math.h>

#define TPB 256
#define ROWS 8

// XOR-swizzle on linear LDS byte offset A (tile = 8 rows x 1024 f32 = 32 KB).
// Flips 16B-granule slot bits [4:7) with key from bits [8:11)^[11:14).
// NOTE: swz does NOT commute with '+'. Within a run whose unswizzled base is
// aligned (offset bits zero) and whose key is constant, swz(A+16k)=swz(A)^16k.
// All run offsets below are applied with XOR for exactly this reason.
__device__ __forceinline__ unsigned swz(unsigned A) {
    return A ^ ((((A >> 8) ^ (A >> 11)) & 7u) << 4);
}

__device__ __forceinline__ float4 ldsrd(const char* ldsb, unsigned A) {
    return *(const float4*)(ldsb + A);
}

// One stage of block size N (N>=64) in LDS.
// Thread = (row, tt): one "oct task" = 8 consecutive pair-indices u in both
// halves of one block -> 32 outputs, all as aligned b128 runs.
template<int N>
__device__ __forceinline__ void lds_stage(char* ldsb, unsigned rb, unsigned tt,
                                          float p, float p1, float p2) {
    constexpr unsigned H = N / 2;
    constexpr int L2 = (N == 1024) ? 5 : (N == 512) ? 4 : (N == 256) ? 3
                     : (N == 128) ? 2 : 1;                  // log2(N/32)
    const unsigned b  = tt >> L2;
    const unsigned s  = tt & ((N / 32) - 1);
    const unsigned u0 = s * 8u;
    const unsigned bc = b * (unsigned)N;

    // Unswizzled bases: j/jm runs are 32B-aligned, e/em runs are 64B-aligned,
    // and no run crosses a 256B line -> key constant, XOR offsets valid.
    const unsigned Aj0  = swz(rb + 4u * (bc + u0));
    const unsigned Aj1  = swz(rb + 4u * (bc + H + u0));
    const unsigned Ajm0 = swz(rb + 4u * (bc + H - 8 - u0));
    const unsigned Ajm1 = swz(rb + 4u * (bc + N - 8 - u0));
    const unsigned Ae   = swz(rb + 4u * (bc + 2 * u0));
    const unsigned Aem  = swz(rb + 4u * (bc + 2 * H - 16 - 2 * u0));

    float j0[8], j1[8], jm0[8], jm1[8], e[16], em[16];
    *(float4*)&j0[0]  = ldsrd(ldsb, Aj0);        *(float4*)&j0[4]  = ldsrd(ldsb, Aj0 ^ 16u);
    *(float4*)&j1[0]  = ldsrd(ldsb, Aj1);        *(float4*)&j1[4]  = ldsrd(ldsb, Aj1 ^ 16u);
    *(float4*)&jm0[0] = ldsrd(ldsb, Ajm0);       *(float4*)&jm0[4] = ldsrd(ldsb, Ajm0 ^ 16u);
    *(float4*)&jm1[0] = ldsrd(ldsb, Ajm1);       *(float4*)&jm1[4] = ldsrd(ldsb, Ajm1 ^ 16u);
    *(float4*)&e[0]   = ldsrd(ldsb, Ae);         *(float4*)&e[4]   = ldsrd(ldsb, Ae ^ 16u);
    *(float4*)&e[8]   = ldsrd(ldsb, Ae ^ 32u);   *(float4*)&e[12]  = ldsrd(ldsb, Ae ^ 48u);
    *(float4*)&em[0]  = ldsrd(ldsb, Aem);        *(float4*)&em[4]  = ldsrd(ldsb, Aem ^ 16u);
    *(float4*)&em[8]  = ldsrd(ldsb, Aem ^ 32u);  *(float4*)&em[12] = ldsrd(ldsb, Aem ^ 48u);

    #pragma unroll
    for (int du = 0; du < 8; ++du) {
        // lo half: j = bc+u, mirror jm = bc+H-1-u, e(j)=2u, e(jm)=2(H-1-u)
        {
            float yj = j0[du], yjm = jm0[7 - du];
            float yej = e[2 * du], yejm = em[14 - 2 * du];
            float a0 = fmaf(p, yej - yj, yj);
            float a1 = fmaf(p, yejm - yjm, yjm);
            float d  = a1 - a0;
            j0[du]      = fmaf(p1, d, a0);   // in-place: each slot read once
            jm0[7 - du] = fmaf(p1, -d, a1);
        }
        // hi half: j = bc+H+u, mirror = bc+N-1-u, e(j)=2u+1, e(m)=2(H-1-u)+1
        {
            float zj = j1[du], zjm = jm1[7 - du];
            float zej = e[2 * du + 1], zejm = em[15 - 2 * du];
            float a0 = fmaf(p, zej - zj, zj);
            float a1 = fmaf(p, zejm - zjm, zjm);
            float d  = a1 - a0;
            j1[du]      = fmaf(p2, d, a0);
            jm1[7 - du] = fmaf(p2, -d, a1);
        }
    }
    __syncthreads();
    // write runs reuse the j-read addresses
    *(float4*)(ldsb + Aj0)          = *(const float4*)&j0[0];
    *(float4*)(ldsb + (Aj0 ^ 16u))  = *(const float4*)&j0[4];
    *(float4*)(ldsb + Aj1)          = *(const float4*)&j1[0];
    *(float4*)(ldsb + (Aj1 ^ 16u))  = *(const float4*)&j1[4];
    *(float4*)(ldsb + Ajm0)         = *(const float4*)&jm0[0];
    *(float4*)(ldsb + (Ajm0 ^ 16u)) = *(const float4*)&jm0[4];
    *(float4*)(ldsb + Ajm1)         = *(const float4*)&jm1[0];
    *(float4*)(ldsb + (Ajm1 ^ 16u)) = *(const float4*)&jm1[4];
    __syncthreads();
}

// Stage of block size N <= 32 fully inside one thread's 32-float chunk.
template<int N>
__device__ __forceinline__ void reg_stage(float* arr, float p, float p1, float p2) {
    constexpr int H = N / 2;
    float tmp[32];
    #pragma unroll
    for (int bb = 0; bb < 32; bb += N) {
        #pragma unroll
        for (int u = 0; u < N / 4; ++u) {
            {   // lo half pair
                int j = bb + u, jm = bb + H - 1 - u;
                int ej = bb + 2 * u, ejm = bb + 2 * H - 2 - 2 * u;
                float a0 = fmaf(p, arr[ej]  - arr[j],  arr[j]);
                float a1 = fmaf(p, arr[ejm] - arr[jm], arr[jm]);
                tmp[j]  = fmaf(p1, a1 - a0, a0);
                tmp[jm] = fmaf(p1, a0 - a1, a1);
            }
            {   // hi half pair
                int j = bb + H + u, jm = bb + 2 * H - 1 - u;
                int ej = bb + 2 * u + 1, ejm = bb + 2 * H - 1 - 2 * u;
                float a0 = fmaf(p, arr[ej]  - arr[j],  arr[j]);
                float a1 = fmaf(p, arr[ejm] - arr[jm], arr[jm]);
                tmp[j]  = fmaf(p2, a1 - a0, a0);
                tmp[jm] = fmaf(p2, a0 - a1, a1);
            }
        }
    }
    #pragma unroll
    for (int v = 0; v < 32; ++v) arr[v] = tmp[v];
}

__global__ void bpp_prep(const float* __restrict__ logits, float* __restrict__ sp) {
    int i = threadIdx.x;
    if (i < 27) sp[i] = 1.0f / (1.0f + expf(-logits[i]));
}

template<bool USE_WS>
__global__ __launch_bounds__(TPB) void bpp_main(const float* __restrict__ x,
                                                float* __restrict__ out,
                                                const float* __restrict__ spws,
                                                const float* __restrict__ logits) {
    __shared__ float lds[ROWS * 1024];
    char* ldsb = (char*)lds;
    const unsigned t = threadIdx.x;
    const size_t gbase = (size_t)blockIdx.x * (ROWS * 1024);

    float prl[27];
    if constexpr (!USE_WS) {
        #pragma unroll
        for (int i = 0; i < 27; ++i) prl[i] = 1.0f / (1.0f + expf(-logits[i]));
    }
    #define PV(i) (USE_WS ? spws[(i)] : prl[(i)])

    // coalesced global -> LDS (each 16B granule swizzled individually)
    const float4* __restrict__ gin = (const float4*)(x + gbase);
    #pragma unroll
    for (int k = 0; k < 8; ++k) {
        float4 v = gin[k * TPB + t];
        unsigned A = (unsigned)k * 4096u + t * 16u;
        *(float4*)(ldsb + swz(A)) = v;
    }
    __syncthreads();

    const unsigned row = t >> 5, tt = t & 31u;
    const unsigned rb = row * 4096u;

    // stages n = 1024..64 (logits rows 8..4)
    lds_stage<1024>(ldsb, rb, tt, PV(24), PV(25), PV(26));
    lds_stage< 512>(ldsb, rb, tt, PV(21), PV(22), PV(23));
    lds_stage< 256>(ldsb, rb, tt, PV(18), PV(19), PV(20));
    lds_stage< 128>(ldsb, rb, tt, PV(15), PV(16), PV(17));
    lds_stage<  64>(ldsb, rb, tt, PV(12), PV(13), PV(14));

    // stages n = 32..4 in registers on the thread's contiguous 32-col chunk
    {
        unsigned A = rb + tt * 128u;      // 128B-aligned -> key constant
        unsigned SB = swz(A);
        float arr[32];
        #pragma unroll
        for (int k = 0; k < 8; ++k)
            *(float4*)&arr[4 * k] = *(const float4*)(ldsb + (SB ^ (16u * k)));
        reg_stage<32>(arr, PV(9), PV(10), PV(11));
        reg_stage<16>(arr, PV(6), PV(7),  PV(8));
        reg_stage< 8>(arr, PV(3), PV(4),  PV(5));
        reg_stage< 4>(arr, PV(0), PV(1),  PV(2));
        #pragma unroll
        for (int k = 0; k < 8; ++k)
            *(float4*)(ldsb + (SB ^ (16u * k))) = *(const float4*)&arr[4 * k];
    }
    __syncthreads();

    // coalesced LDS -> global
    float4* __restrict__ gout = (float4*)(out + gbase);
    #pragma unroll
    for (int k = 0; k < 8; ++k) {
        unsigned A = (unsigned)k * 4096u + t * 16u;
        gout[k * TPB + t] = *(const float4*)(ldsb + swz(A));
    }
    #undef PV
}

extern "C" void kernel_launch(void* const* d_in, const int* in_sizes, int n_in,
                              void* d_out, int out_size, void* d_ws, size_t ws_size,
                              hipStream_t stream) {
    const float* x      = (const float*)d_in[0];
    const float* logits = (const float*)d_in[1];
    float* out = (float*)d_out;
    int rows = in_sizes[0] / 1024;
    int grid = rows / ROWS;
    if (ws_size >= 27 * sizeof(float)) {
        float* sp = (float*)d_ws;
        bpp_prep<<<dim3(1), dim3(32), 0, stream>>>(logits, sp);
        bpp_main<true><<<dim3(grid), dim3(TPB), 0, stream>>>(x, out, sp, logits);
    } else {
        bpp_main<false><<<dim3(grid), dim3(TPB), 0, stream>>>(x, out, nullptr, logits);
    }
}